// Round 4
// baseline (29894.339 us; speedup 1.0000x reference)
//
#include <hip/hip_runtime.h>
#include <hip/hip_bf16.h>

#define BB 32
#define TT 128
#define PP 196
#define ENC 2048
#define DEC 512
#define ATT 512
#define EMB 512
#define VV 10000
#define G4 2048   // 4*DEC
#define KX 2560   // EMB+ENC

typedef unsigned short u16;
typedef unsigned int u32;

__device__ __forceinline__ float bf2f(u16 u) { return __uint_as_float(((u32)u) << 16); }
__device__ __forceinline__ u16 f2bf(float f) {
  u32 x = __float_as_uint(f);
  u32 r = (x + 0x7fffu + ((x >> 16) & 1u)) >> 16;
  return (u16)r;
}
__device__ __forceinline__ void unpack8(uint4 v, float* f) {
  f[0] = __uint_as_float(v.x << 16); f[1] = __uint_as_float(v.x & 0xffff0000u);
  f[2] = __uint_as_float(v.y << 16); f[3] = __uint_as_float(v.y & 0xffff0000u);
  f[4] = __uint_as_float(v.z << 16); f[5] = __uint_as_float(v.z & 0xffff0000u);
  f[6] = __uint_as_float(v.w << 16); f[7] = __uint_as_float(v.w & 0xffff0000u);
}
__device__ __forceinline__ void load8(const float* __restrict__ p, float* f) {
  float4 a = ((const float4*)p)[0];
  float4 b = ((const float4*)p)[1];
  f[0] = a.x; f[1] = a.y; f[2] = a.z; f[3] = a.w;
  f[4] = b.x; f[5] = b.y; f[6] = b.z; f[7] = b.w;
}
__device__ __forceinline__ float sigf(float x) { return 1.0f / (1.0f + __expf(-x)); }

// ---------- init: mean_img -> h0, c0 ----------
__global__ __launch_bounds__(256) void k_init(const float* __restrict__ imgs,
    const float* __restrict__ ihW, const float* __restrict__ ihb,
    const float* __restrict__ icW, const float* __restrict__ icb,
    float* __restrict__ h, float* __restrict__ c) {
  __shared__ float mean_s[ENC];
  int b = blockIdx.x, tid = threadIdx.x;
  for (int i = 0; i < ENC / 256; i++) {
    int ch = tid + i * 256;
    float s = 0.f;
    for (int p = 0; p < PP; p++) s += imgs[(size_t)(b * PP + p) * ENC + ch];
    mean_s[ch] = s * (1.0f / PP);
  }
  __syncthreads();
  for (int i = 0; i < 4; i++) {
    int o = tid + i * 256;            // 0..1023
    int j = o & 511; int which = o >> 9;
    const float* W = which ? icW : ihW;
    const float* bias = which ? icb : ihb;
    const float* wr = W + (size_t)j * ENC;
    float acc = 0.f;
    for (int k = 0; k < ENC; k += 8) {
      float wf[8]; load8(wr + k, wf);
#pragma unroll
      for (int u = 0; u < 8; u++) acc += wf[u] * mean_s[k + u];
    }
    acc += bias[j];
    if (which) c[b * DEC + j] = acc; else h[b * DEC + j] = acc;
  }
}

// ---------- att1 = imgs @ enc_att_W.T + b  (6272 x 512, K=2048), bf16 out ----------
__global__ __launch_bounds__(512) void k_att1(const float* __restrict__ imgs,
    const float* __restrict__ W, const float* __restrict__ bias, u16* __restrict__ att1) {
  __shared__ float a_s[8 * ENC];   // [k][m] layout: a_s[k*8+m]
  int m0 = blockIdx.x * 8, tid = threadIdx.x;
  for (int i = 0; i < (8 * ENC) / 512; i++) {
    int flat = i * 512 + tid;
    int m = flat >> 11, k = flat & 2047;
    a_s[k * 8 + m] = imgs[(size_t)(m0 + m) * ENC + k];
  }
  __syncthreads();
  int j = tid;
  const float* wr = W + (size_t)j * ENC;
  float acc[8] = {0,0,0,0,0,0,0,0};
  for (int k = 0; k < ENC; k += 8) {
    float wf[8]; load8(wr + k, wf);
#pragma unroll
    for (int u = 0; u < 8; u++) {
      const float4* ap = (const float4*)&a_s[(k + u) * 8];
      float4 a0 = ap[0], a1 = ap[1];
      acc[0] += wf[u] * a0.x; acc[1] += wf[u] * a0.y;
      acc[2] += wf[u] * a0.z; acc[3] += wf[u] * a0.w;
      acc[4] += wf[u] * a1.x; acc[5] += wf[u] * a1.y;
      acc[6] += wf[u] * a1.z; acc[7] += wf[u] * a1.w;
    }
  }
  float bj = bias[j];
#pragma unroll
  for (int m = 0; m < 8; m++)
    att1[(size_t)(m0 + m) * ATT + j] = f2bf(acc[m] + bj);
}

// ---------- per-step phase 1: att2, gate, h@W_hh.T (N=4608, K=512, all b) ----------
__global__ __launch_bounds__(256) void k_step1(const float* __restrict__ h,
    const float* __restrict__ decW, const float* __restrict__ decb,
    const float* __restrict__ fbW, const float* __restrict__ fbb,
    const float* __restrict__ Whh, const float* __restrict__ bhh,
    float* __restrict__ att2, float* __restrict__ gate, float* __restrict__ hWhh) {
  __shared__ float h_s[DEC * 33];   // [k][b], pad 33
  int tid = threadIdx.x;
  for (int i = 0; i < 64; i++) {
    int flat = i * 256 + tid;
    int b = flat >> 9, k = flat & 511;
    h_s[k * 33 + b] = h[b * DEC + k];
  }
  __syncthreads();
  int j = blockIdx.x * 8 + (tid >> 5);
  int b = tid & 31;
  const float* Wrow; float biasv; int region;
  if (j < ATT)            { Wrow = decW + (size_t)j * DEC;              biasv = decb[j];           region = 0; }
  else if (j < ATT + ENC) { Wrow = fbW + (size_t)(j - ATT) * DEC;       biasv = fbb[j - ATT];      region = 1; }
  else                    { Wrow = Whh + (size_t)(j - ATT - ENC) * DEC; biasv = bhh[j - ATT - ENC]; region = 2; }
  float acc = 0.f;
  for (int k = 0; k < DEC; k += 8) {
    float wf[8]; load8(Wrow + k, wf);
#pragma unroll
    for (int u = 0; u < 8; u++) acc += wf[u] * h_s[(k + u) * 33 + b];
  }
  acc += biasv;
  if (region == 0) att2[b * ATT + j] = acc;
  else if (region == 1) gate[b * ENC + (j - ATT)] = sigf(acc);
  else hWhh[b * G4 + (j - ATT - ENC)] = acc;
}

// ---------- per-step: e, softmax, alpha (one block per b) ----------
__global__ __launch_bounds__(256) void k_att(int t, const int* __restrict__ bxlen,
    const u16* __restrict__ att1, const float* __restrict__ att2,
    const float* __restrict__ faW, const float* __restrict__ fab,
    float* __restrict__ alpha_ws, float* __restrict__ out_alphas) {
  int b = blockIdx.x;
  if (t >= bxlen[b]) return;
  __shared__ float a2[ATT];
  __shared__ float w_s[ATT];
  __shared__ float red[256];
  int tid = threadIdx.x;
  for (int i = tid; i < ATT; i += 256) { a2[i] = att2[b * ATT + i]; w_s[i] = faW[i]; }
  __syncthreads();
  float e = -1e30f;
  if (tid < PP) {
    const uint4* ar = (const uint4*)(att1 + (size_t)(b * PP + tid) * ATT);
    float acc = 0.f;
    for (int k = 0; k < ATT; k += 8) {
      float af[8]; unpack8(ar[k >> 3], af);
#pragma unroll
      for (int u = 0; u < 8; u++) {
        float v = af[u] + a2[k + u];
        acc += fmaxf(v, 0.f) * w_s[k + u];
      }
    }
    e = acc + fab[0];
  }
  red[tid] = e; __syncthreads();
  for (int s = 128; s > 0; s >>= 1) { if (tid < s) red[tid] = fmaxf(red[tid], red[tid + s]); __syncthreads(); }
  float mx = red[0]; __syncthreads();
  float ex = (tid < PP) ? __expf(e - mx) : 0.f;
  red[tid] = ex; __syncthreads();
  for (int s = 128; s > 0; s >>= 1) { if (tid < s) red[tid] += red[tid + s]; __syncthreads(); }
  float inv = 1.0f / red[0];
  if (tid < PP) {
    float al = ex * inv;
    alpha_ws[b * PP + tid] = al;
    out_alphas[((size_t)b * TT + t) * PP + tid] = al;
  }
}

// ---------- per-step: awe = alpha . imgs; xawe = gate*awe ----------
__global__ __launch_bounds__(256) void k_awe(int t, const int* __restrict__ bxlen,
    const float* __restrict__ imgs, const float* __restrict__ alpha_ws,
    const float* __restrict__ gate, float* __restrict__ xawe) {
  int b = blockIdx.x >> 3, chunk = blockIdx.x & 7;
  if (t >= bxlen[b]) return;
  __shared__ float al[PP];
  int tid = threadIdx.x;
  if (tid < PP) al[tid] = alpha_ws[b * PP + tid];
  __syncthreads();
  int ch = chunk * 256 + tid;
  float acc = 0.f;
  for (int p = 0; p < PP; p++)
    acc += al[p] * imgs[(size_t)(b * PP + p) * ENC + ch];
  xawe[b * ENC + ch] = gate[b * ENC + ch] * acc;
}

// ---------- per-step: gates = x @ W_ih.T + b_ih + hWhh  (N=2048, K=2560) ----------
__global__ __launch_bounds__(256) void k_gates(int t, const int* __restrict__ bx,
    const float* __restrict__ embW, const float* __restrict__ xawe,
    const float* __restrict__ Wih, const float* __restrict__ bih,
    const float* __restrict__ hWhh, float* __restrict__ gates) {
  __shared__ float x_s[512 * 33];
  int tid = threadIdx.x;
  int j = blockIdx.x * 8 + (tid >> 5);
  int b = tid & 31;
  const float* wr = Wih + (size_t)j * KX;
  float acc = 0.f;
  for (int kc = 0; kc < KX; kc += 512) {
    __syncthreads();
    for (int i = 0; i < 64; i++) {
      int flat = i * 256 + tid;
      int bb = flat >> 9, k = flat & 511;
      int kg = kc + k;
      float v;
      if (kg < EMB) v = embW[(size_t)bx[bb * TT + t] * EMB + kg];
      else v = xawe[bb * ENC + (kg - EMB)];
      x_s[k * 33 + bb] = v;
    }
    __syncthreads();
    for (int k = 0; k < 512; k += 8) {
      float wf[8]; load8(wr + kc + k, wf);
#pragma unroll
      for (int u = 0; u < 8; u++) acc += wf[u] * x_s[(k + u) * 33 + b];
    }
  }
  gates[b * G4 + j] = acc + bih[j] + hWhh[b * G4 + j];
}

// ---------- per-step: LSTM pointwise ----------
__global__ __launch_bounds__(256) void k_lstm(int t, const int* __restrict__ bxlen,
    const float* __restrict__ gates, float* __restrict__ h, float* __restrict__ c) {
  int idx = blockIdx.x * 256 + threadIdx.x;
  int b = idx >> 9, d = idx & 511;
  if (t >= bxlen[b]) return;
  float i_ = sigf(gates[b * G4 + d]);
  float f_ = sigf(gates[b * G4 + 512 + d]);
  float g_ = tanhf(gates[b * G4 + 1024 + d]);
  float o_ = sigf(gates[b * G4 + 1536 + d]);
  float cn = f_ * c[b * DEC + d] + i_ * g_;
  float hn = o_ * tanhf(cn);
  c[b * DEC + d] = cn;
  h[b * DEC + d] = hn;
}

// ---------- per-step: preds = h_new @ fc_W.T + fc_b  (N=10000, K=512) ----------
__global__ __launch_bounds__(256) void k_fc(int t, const int* __restrict__ bxlen,
    const float* __restrict__ h, const float* __restrict__ fcW, const float* __restrict__ fcb,
    float* __restrict__ preds) {
  __shared__ float h_s[DEC * 33];
  int tid = threadIdx.x;
  for (int i = 0; i < 64; i++) {
    int flat = i * 256 + tid;
    int b = flat >> 9, k = flat & 511;
    h_s[k * 33 + b] = h[b * DEC + k];
  }
  __syncthreads();
  int j = blockIdx.x * 8 + (tid >> 5);
  int b = tid & 31;
  const float* wr = fcW + (size_t)j * DEC;
  float acc = 0.f;
  for (int k = 0; k < DEC; k += 8) {
    float wf[8]; load8(wr + k, wf);
#pragma unroll
    for (int u = 0; u < 8; u++) acc += wf[u] * h_s[(k + u) * 33 + b];
  }
  if (t < bxlen[b])
    preds[((size_t)b * TT + t) * VV + j] = acc + fcb[j];
}

extern "C" void kernel_launch(void* const* d_in, const int* in_sizes, int n_in,
                              void* d_out, int out_size, void* d_ws, size_t ws_size,
                              hipStream_t stream) {
  const float* imgs = (const float*)d_in[0];
  const int* bx     = (const int*)d_in[1];
  const int* bxlen  = (const int*)d_in[2];
  const float* embW = (const float*)d_in[3];
  const float* encW = (const float*)d_in[4];
  const float* encb = (const float*)d_in[5];
  const float* decW = (const float*)d_in[6];
  const float* decb = (const float*)d_in[7];
  const float* faW  = (const float*)d_in[8];
  const float* fab  = (const float*)d_in[9];
  const float* ihW  = (const float*)d_in[10];
  const float* ihb  = (const float*)d_in[11];
  const float* icW  = (const float*)d_in[12];
  const float* icb  = (const float*)d_in[13];
  const float* fbW  = (const float*)d_in[14];
  const float* fbb  = (const float*)d_in[15];
  const float* Wih  = (const float*)d_in[16];
  const float* bih  = (const float*)d_in[17];
  const float* Whh  = (const float*)d_in[18];
  const float* bhh  = (const float*)d_in[19];
  const float* fcW  = (const float*)d_in[20];
  const float* fcb  = (const float*)d_in[21];

  float* out_preds  = (float*)d_out;                       // (B,T,V) f32
  float* out_alphas = out_preds + (size_t)BB * TT * VV;    // (B,T,P) f32

  char* wsb = (char*)d_ws;
  u16* att1 = (u16*)wsb;                       // 6.42 MB bf16
  size_t off = ((size_t)BB * PP * ATT * 2 + 15) & ~(size_t)15;
  float* fb    = (float*)(wsb + off);          // ~1.27 MB of f32 state
  float* h     = fb;
  float* c     = h + BB * DEC;
  float* att2  = c + BB * DEC;
  float* gate  = att2 + BB * ATT;
  float* hWhh  = gate + BB * ENC;
  float* xawe  = hWhh + BB * G4;
  float* gates = xawe + BB * ENC;
  float* alpha = gates + BB * G4;

  hipMemsetAsync(d_out, 0, (size_t)out_size * sizeof(float), stream);

  k_init<<<BB, 256, 0, stream>>>(imgs, ihW, ihb, icW, icb, h, c);
  k_att1<<<(BB * PP) / 8, 512, 0, stream>>>(imgs, encW, encb, att1);

  for (int t = 0; t < TT; t++) {
    k_step1<<<4608 / 8, 256, 0, stream>>>(h, decW, decb, fbW, fbb, Whh, bhh, att2, gate, hWhh);
    k_att<<<BB, 256, 0, stream>>>(t, bxlen, att1, att2, faW, fab, alpha, out_alphas);
    k_awe<<<BB * 8, 256, 0, stream>>>(t, bxlen, imgs, alpha, gate, xawe);
    k_gates<<<G4 / 8, 256, 0, stream>>>(t, bx, embW, xawe, Wih, bih, hWhh, gates);
    k_lstm<<<(BB * DEC) / 256, 256, 0, stream>>>(t, bxlen, gates, h, c);
    k_fc<<<VV / 8, 256, 0, stream>>>(t, bxlen, h, fcW, fcb, out_preds);
  }
}

// Round 5
// 7248.461 us; speedup vs baseline: 4.1242x; 4.1242x over previous
//
#include <hip/hip_runtime.h>
#include <hip/hip_bf16.h>

#define BB 32
#define TT 128
#define PP 196
#define ENC 2048
#define DEC 512
#define ATT 512
#define EMB 512
#define VV 10000
#define G4 2048   // 4*DEC
#define KX 2560   // EMB+ENC

typedef unsigned short u16;
typedef unsigned int u32;
typedef __attribute__((ext_vector_type(8))) short short8;
typedef __attribute__((ext_vector_type(4))) float f32x4;

__device__ __forceinline__ float bf2f(u16 u) { return __uint_as_float(((u32)u) << 16); }
__device__ __forceinline__ u16 f2bf(float f) {
  u32 x = __float_as_uint(f);
  u32 r = (x + 0x7fffu + ((x >> 16) & 1u)) >> 16;
  return (u16)r;
}
__device__ __forceinline__ void unpack8(uint4 v, float* f) {
  f[0] = __uint_as_float(v.x << 16); f[1] = __uint_as_float(v.x & 0xffff0000u);
  f[2] = __uint_as_float(v.y << 16); f[3] = __uint_as_float(v.y & 0xffff0000u);
  f[4] = __uint_as_float(v.z << 16); f[5] = __uint_as_float(v.z & 0xffff0000u);
  f[6] = __uint_as_float(v.w << 16); f[7] = __uint_as_float(v.w & 0xffff0000u);
}
__device__ __forceinline__ void load8(const float* __restrict__ p, float* f) {
  float4 a = ((const float4*)p)[0];
  float4 b = ((const float4*)p)[1];
  f[0] = a.x; f[1] = a.y; f[2] = a.z; f[3] = a.w;
  f[4] = b.x; f[5] = b.y; f[6] = b.z; f[7] = b.w;
}
__device__ __forceinline__ float sigf(float x) { return 1.0f / (1.0f + __expf(-x)); }
__device__ __forceinline__ short8 ld_frag(const u16* __restrict__ p) {
  union { uint4 u; short8 s; } cv;
  cv.u = *(const uint4*)p;
  return cv.s;
}

// ---------- one-time f32 -> bf16 conversion ----------
__global__ __launch_bounds__(256) void k_cvt(const float* __restrict__ src, u16* __restrict__ dst, int n) {
  int i0 = (blockIdx.x * 256 + threadIdx.x) * 8;
  if (i0 >= n) return;
  float f[8]; load8(src + i0, f);
  u16 o[8];
#pragma unroll
  for (int u = 0; u < 8; u++) o[u] = f2bf(f[u]);
  *(uint4*)(dst + i0) = *(const uint4*)o;
}

// ---------- init: mean_img -> h0 (bf16), c0 (f32) ----------
__global__ __launch_bounds__(256) void k_init(const float* __restrict__ imgs,
    const float* __restrict__ ihW, const float* __restrict__ ihb,
    const float* __restrict__ icW, const float* __restrict__ icb,
    u16* __restrict__ h_bf, float* __restrict__ c) {
  __shared__ float mean_s[ENC];
  int b = blockIdx.x, tid = threadIdx.x;
  for (int i = 0; i < ENC / 256; i++) {
    int ch = tid + i * 256;
    float s = 0.f;
    for (int p = 0; p < PP; p++) s += imgs[(size_t)(b * PP + p) * ENC + ch];
    mean_s[ch] = s * (1.0f / PP);
  }
  __syncthreads();
  for (int i = 0; i < 4; i++) {
    int o = tid + i * 256;
    int j = o & 511; int which = o >> 9;
    const float* W = which ? icW : ihW;
    const float* bias = which ? icb : ihb;
    const float* wr = W + (size_t)j * ENC;
    float acc = 0.f;
    for (int k = 0; k < ENC; k += 8) {
      float wf[8]; load8(wr + k, wf);
#pragma unroll
      for (int u = 0; u < 8; u++) acc += wf[u] * mean_s[k + u];
    }
    acc += bias[j];
    if (which) c[b * DEC + j] = acc; else h_bf[b * DEC + j] = f2bf(acc);
  }
}

// ---------- att1 = imgs @ enc_att_W.T + b  (6272 x 512, K=2048), bf16 out ----------
__global__ __launch_bounds__(512) void k_att1(const float* __restrict__ imgs,
    const float* __restrict__ W, const float* __restrict__ bias, u16* __restrict__ att1) {
  __shared__ float a_s[8 * ENC];
  int m0 = blockIdx.x * 8, tid = threadIdx.x;
  for (int i = 0; i < (8 * ENC) / 512; i++) {
    int flat = i * 512 + tid;
    int m = flat >> 11, k = flat & 2047;
    a_s[k * 8 + m] = imgs[(size_t)(m0 + m) * ENC + k];
  }
  __syncthreads();
  int j = tid;
  const float* wr = W + (size_t)j * ENC;
  float acc[8] = {0,0,0,0,0,0,0,0};
  for (int k = 0; k < ENC; k += 8) {
    float wf[8]; load8(wr + k, wf);
#pragma unroll
    for (int u = 0; u < 8; u++) {
      const float4* ap = (const float4*)&a_s[(k + u) * 8];
      float4 a0 = ap[0], a1 = ap[1];
      acc[0] += wf[u] * a0.x; acc[1] += wf[u] * a0.y;
      acc[2] += wf[u] * a0.z; acc[3] += wf[u] * a0.w;
      acc[4] += wf[u] * a1.x; acc[5] += wf[u] * a1.y;
      acc[6] += wf[u] * a1.z; acc[7] += wf[u] * a1.w;
    }
  }
  float bj = bias[j];
#pragma unroll
  for (int m = 0; m < 8; m++)
    att1[(size_t)(m0 + m) * ATT + j] = f2bf(acc[m] + bj);
}

// ---------- per-step: MFMA GEMM over W3=[dec|fb|whh] (4608x512) x h_bf^T -> att2/gate/hWhh ----------
// 1 wave/block, 1 j-tile (16 j), 2 b-tiles. D[j][b]: A=W row frag, B=h row frag.
__global__ __launch_bounds__(64) void k_step1(const u16* __restrict__ W3,
    const float* __restrict__ decb, const float* __restrict__ fbb, const float* __restrict__ bhh,
    const u16* __restrict__ h_bf,
    float* __restrict__ att2, float* __restrict__ gate, float* __restrict__ hWhh) {
  int lane = threadIdx.x;
  int j0 = blockIdx.x * 16;
  int m = lane & 15, quad = lane >> 4;
  const u16* arow = W3 + (size_t)(j0 + m) * DEC + quad * 8;
  const u16* xb0 = h_bf + (size_t)m * DEC + quad * 8;
  const u16* xb1 = h_bf + (size_t)(16 + m) * DEC + quad * 8;
  f32x4 acc0 = {0.f,0.f,0.f,0.f}, acc1 = {0.f,0.f,0.f,0.f};
  for (int k = 0; k < DEC; k += 32) {
    short8 a = ld_frag(arow + k);
    short8 x0 = ld_frag(xb0 + k);
    short8 x1 = ld_frag(xb1 + k);
    acc0 = __builtin_amdgcn_mfma_f32_16x16x32_bf16(a, x0, acc0, 0, 0, 0);
    acc1 = __builtin_amdgcn_mfma_f32_16x16x32_bf16(a, x1, acc1, 0, 0, 0);
  }
  // store: col=lane&15 = b, row=quad*4+reg = j offset
  int jj = j0 + quad * 4;
  int b0 = m, b1 = 16 + m;
#pragma unroll
  for (int r = 0; r < 4; r++) {
    int j = jj + r;
    float v0 = acc0[r], v1 = acc1[r];
    if (j0 < ATT) {             // att2 region
      float bia = decb[j];
      att2[b0 * ATT + j] = v0 + bia;
      att2[b1 * ATT + j] = v1 + bia;
    } else if (j0 < ATT + ENC) { // gate region (sigmoid)
      int g = j - ATT;
      float bia = fbb[g];
      gate[b0 * ENC + g] = sigf(v0 + bia);
      gate[b1 * ENC + g] = sigf(v1 + bia);
    } else {                     // hWhh region
      int g = j - ATT - ENC;
      float bia = bhh[g];
      hWhh[b0 * G4 + g] = v0 + bia;
      hWhh[b1 * G4 + g] = v1 + bia;
    }
  }
}

// ---------- per-step: e, softmax, alpha (one block per b) ----------
__global__ __launch_bounds__(256) void k_att(int t, const int* __restrict__ bxlen,
    const u16* __restrict__ att1, const float* __restrict__ att2,
    const float* __restrict__ faW, const float* __restrict__ fab,
    float* __restrict__ alpha_ws, float* __restrict__ out_alphas) {
  int b = blockIdx.x;
  if (t >= bxlen[b]) return;
  __shared__ float a2[ATT];
  __shared__ float w_s[ATT];
  __shared__ float red[256];
  int tid = threadIdx.x;
  for (int i = tid; i < ATT; i += 256) { a2[i] = att2[b * ATT + i]; w_s[i] = faW[i]; }
  __syncthreads();
  float e = -1e30f;
  if (tid < PP) {
    const uint4* ar = (const uint4*)(att1 + (size_t)(b * PP + tid) * ATT);
    float acc = 0.f;
    for (int k = 0; k < ATT; k += 8) {
      float af[8]; unpack8(ar[k >> 3], af);
#pragma unroll
      for (int u = 0; u < 8; u++) {
        float v = af[u] + a2[k + u];
        acc += fmaxf(v, 0.f) * w_s[k + u];
      }
    }
    e = acc + fab[0];
  }
  red[tid] = e; __syncthreads();
  for (int s = 128; s > 0; s >>= 1) { if (tid < s) red[tid] = fmaxf(red[tid], red[tid + s]); __syncthreads(); }
  float mx = red[0]; __syncthreads();
  float ex = (tid < PP) ? __expf(e - mx) : 0.f;
  red[tid] = ex; __syncthreads();
  for (int s = 128; s > 0; s >>= 1) { if (tid < s) red[tid] += red[tid + s]; __syncthreads(); }
  float inv = 1.0f / red[0];
  if (tid < PP) {
    float al = ex * inv;
    alpha_ws[b * PP + tid] = al;
    out_alphas[((size_t)b * TT + t) * PP + tid] = al;
  }
}

// ---------- per-step: x_bf assembly: emb gather + gate*awe (bf16) ----------
// grid = BB*9: chunk 0..7 -> awe over 256 ch; chunk 8 -> emb copy
__global__ __launch_bounds__(256) void k_awe(int t, const int* __restrict__ bxlen,
    const int* __restrict__ bx, const float* __restrict__ embW,
    const u16* __restrict__ imgs_bf, const float* __restrict__ alpha_ws,
    const float* __restrict__ gate, u16* __restrict__ x_bf) {
  int b = blockIdx.x / 9, chunk = blockIdx.x % 9;
  if (t >= bxlen[b]) return;
  int tid = threadIdx.x;
  if (chunk == 8) {
    int tok = bx[b * TT + t];
    int ch = tid * 2;
    x_bf[b * KX + ch]     = f2bf(embW[(size_t)tok * EMB + ch]);
    x_bf[b * KX + ch + 1] = f2bf(embW[(size_t)tok * EMB + ch + 1]);
    return;
  }
  __shared__ float al[PP];
  if (tid < PP) al[tid] = alpha_ws[b * PP + tid];
  __syncthreads();
  int ch = chunk * 256 + tid;
  float acc = 0.f;
  for (int p = 0; p < PP; p++)
    acc += al[p] * bf2f(imgs_bf[(size_t)(b * PP + p) * ENC + ch]);
  x_bf[b * KX + EMB + ch] = f2bf(gate[b * ENC + ch] * acc);
}

// ---------- per-step: gates partials via MFMA, split-K 4x640 ----------
__global__ __launch_bounds__(64) void k_gates(const u16* __restrict__ Wih_bf,
    const u16* __restrict__ x_bf, float* __restrict__ gates_p) {
  int lane = threadIdx.x;
  int j0 = blockIdx.x * 16;
  int kc = blockIdx.y * 640;
  int m = lane & 15, quad = lane >> 4;
  const u16* arow = Wih_bf + (size_t)(j0 + m) * KX + kc + quad * 8;
  const u16* xb0 = x_bf + (size_t)m * KX + kc + quad * 8;
  const u16* xb1 = x_bf + (size_t)(16 + m) * KX + kc + quad * 8;
  f32x4 acc0 = {0.f,0.f,0.f,0.f}, acc1 = {0.f,0.f,0.f,0.f};
  for (int k = 0; k < 640; k += 32) {
    short8 a = ld_frag(arow + k);
    short8 x0 = ld_frag(xb0 + k);
    short8 x1 = ld_frag(xb1 + k);
    acc0 = __builtin_amdgcn_mfma_f32_16x16x32_bf16(a, x0, acc0, 0, 0, 0);
    acc1 = __builtin_amdgcn_mfma_f32_16x16x32_bf16(a, x1, acc1, 0, 0, 0);
  }
  float* gp = gates_p + (size_t)blockIdx.y * BB * G4;
  int jj = j0 + quad * 4;
  int b0 = m, b1 = 16 + m;
#pragma unroll
  for (int r = 0; r < 4; r++) {
    int j = jj + r;
    gp[b0 * G4 + j] = acc0[r];
    gp[b1 * G4 + j] = acc1[r];
  }
}

// ---------- per-step: LSTM pointwise (sums split-K partials) ----------
__global__ __launch_bounds__(256) void k_lstm(int t, const int* __restrict__ bxlen,
    const float* __restrict__ gates_p, const float* __restrict__ bih,
    const float* __restrict__ hWhh,
    u16* __restrict__ h_bf, float* __restrict__ c) {
  int idx = blockIdx.x * 256 + threadIdx.x;
  int b = idx >> 9, d = idx & 511;
  if (t >= bxlen[b]) return;
  float pre[4];
#pragma unroll
  for (int g = 0; g < 4; g++) {
    int j = g * 512 + d;
    float s = bih[j] + hWhh[b * G4 + j];
#pragma unroll
    for (int cc = 0; cc < 4; cc++) s += gates_p[(size_t)cc * BB * G4 + b * G4 + j];
    pre[g] = s;
  }
  float i_ = sigf(pre[0]);
  float f_ = sigf(pre[1]);
  float g_ = tanhf(pre[2]);
  float o_ = sigf(pre[3]);
  float cn = f_ * c[b * DEC + d] + i_ * g_;
  float hn = o_ * tanhf(cn);
  c[b * DEC + d] = cn;
  h_bf[b * DEC + d] = f2bf(hn);
}

// ---------- per-step: preds = h_new @ fc_W.T + fc_b via MFMA (625 j-tiles) ----------
__global__ __launch_bounds__(64) void k_fc(int t, const int* __restrict__ bxlen,
    const u16* __restrict__ fcW_bf, const float* __restrict__ fcb,
    const u16* __restrict__ h_bf, float* __restrict__ preds) {
  int lane = threadIdx.x;
  int j0 = blockIdx.x * 16;
  int m = lane & 15, quad = lane >> 4;
  const u16* arow = fcW_bf + (size_t)(j0 + m) * DEC + quad * 8;
  const u16* xb0 = h_bf + (size_t)m * DEC + quad * 8;
  const u16* xb1 = h_bf + (size_t)(16 + m) * DEC + quad * 8;
  f32x4 acc0 = {0.f,0.f,0.f,0.f}, acc1 = {0.f,0.f,0.f,0.f};
  for (int k = 0; k < DEC; k += 32) {
    short8 a = ld_frag(arow + k);
    short8 x0 = ld_frag(xb0 + k);
    short8 x1 = ld_frag(xb1 + k);
    acc0 = __builtin_amdgcn_mfma_f32_16x16x32_bf16(a, x0, acc0, 0, 0, 0);
    acc1 = __builtin_amdgcn_mfma_f32_16x16x32_bf16(a, x1, acc1, 0, 0, 0);
  }
  int jj = j0 + quad * 4;
  int b0 = m, b1 = 16 + m;
  bool act0 = (t < bxlen[b0]);
  bool act1 = (t < bxlen[b1]);
#pragma unroll
  for (int r = 0; r < 4; r++) {
    int j = jj + r;
    float bia = fcb[j];
    if (act0) preds[((size_t)b0 * TT + t) * VV + j] = acc0[r] + bia;
    if (act1) preds[((size_t)b1 * TT + t) * VV + j] = acc1[r] + bia;
  }
}

extern "C" void kernel_launch(void* const* d_in, const int* in_sizes, int n_in,
                              void* d_out, int out_size, void* d_ws, size_t ws_size,
                              hipStream_t stream) {
  const float* imgs = (const float*)d_in[0];
  const int* bx     = (const int*)d_in[1];
  const int* bxlen  = (const int*)d_in[2];
  const float* embW = (const float*)d_in[3];
  const float* encW = (const float*)d_in[4];
  const float* encb = (const float*)d_in[5];
  const float* decW = (const float*)d_in[6];
  const float* decb = (const float*)d_in[7];
  const float* faW  = (const float*)d_in[8];
  const float* fab  = (const float*)d_in[9];
  const float* ihW  = (const float*)d_in[10];
  const float* ihb  = (const float*)d_in[11];
  const float* icW  = (const float*)d_in[12];
  const float* icb  = (const float*)d_in[13];
  const float* fbW  = (const float*)d_in[14];
  const float* fbb  = (const float*)d_in[15];
  const float* Wih  = (const float*)d_in[16];
  const float* bih  = (const float*)d_in[17];
  const float* Whh  = (const float*)d_in[18];
  const float* bhh  = (const float*)d_in[19];
  const float* fcW  = (const float*)d_in[20];
  const float* fcb  = (const float*)d_in[21];

  float* out_preds  = (float*)d_out;
  float* out_alphas = out_preds + (size_t)BB * TT * VV;

  char* wsb = (char*)d_ws;
  size_t off = 0;
  u16* imgs_bf = (u16*)(wsb + off); off += (size_t)BB * PP * ENC * 2;   // 25.69 MB
  u16* W3_bf   = (u16*)(wsb + off); off += (size_t)4608 * DEC * 2;      // 4.72 MB
  u16* Wih_bf  = (u16*)(wsb + off); off += (size_t)G4 * KX * 2;         // 10.49 MB
  u16* fcW_bf  = (u16*)(wsb + off); off += (size_t)VV * DEC * 2;        // 10.24 MB
  u16* att1    = (u16*)(wsb + off); off += (size_t)BB * PP * ATT * 2;   // 6.42 MB
  u16* x_bf    = (u16*)(wsb + off); off += (size_t)BB * KX * 2;         // 160 KB
  u16* h_bf    = (u16*)(wsb + off); off += (size_t)BB * DEC * 2;        // 32 KB
  float* c      = (float*)(wsb + off); off += (size_t)BB * DEC * 4;
  float* att2   = (float*)(wsb + off); off += (size_t)BB * ATT * 4;
  float* gate   = (float*)(wsb + off); off += (size_t)BB * ENC * 4;
  float* hWhh   = (float*)(wsb + off); off += (size_t)BB * G4 * 4;
  float* gates_p = (float*)(wsb + off); off += (size_t)4 * BB * G4 * 4; // 1 MB
  float* alpha  = (float*)(wsb + off); off += (size_t)BB * PP * 4;

  hipMemsetAsync(d_out, 0, (size_t)out_size * sizeof(float), stream);

  // one-time conversions (per call; graph replays them)
  k_cvt<<<(BB * PP * ENC) / 2048, 256, 0, stream>>>(imgs, imgs_bf, BB * PP * ENC);
  k_cvt<<<(DEC * DEC) / 2048, 256, 0, stream>>>(decW, W3_bf, DEC * DEC);
  k_cvt<<<(ENC * DEC) / 2048, 256, 0, stream>>>(fbW, W3_bf + (size_t)DEC * DEC, ENC * DEC);
  k_cvt<<<(G4 * DEC) / 2048, 256, 0, stream>>>(Whh, W3_bf + (size_t)(DEC + ENC) * DEC, G4 * DEC);
  k_cvt<<<(G4 * KX) / 2048, 256, 0, stream>>>(Wih, Wih_bf, G4 * KX);
  k_cvt<<<(VV * DEC) / 2048, 256, 0, stream>>>(fcW, fcW_bf, VV * DEC);

  k_init<<<BB, 256, 0, stream>>>(imgs, ihW, ihb, icW, icb, h_bf, c);
  k_att1<<<(BB * PP) / 8, 512, 0, stream>>>(imgs, encW, encb, att1);

  for (int t = 0; t < TT; t++) {
    k_step1<<<4608 / 16, 64, 0, stream>>>(W3_bf, decb, fbb, bhh, h_bf, att2, gate, hWhh);
    k_att<<<BB, 256, 0, stream>>>(t, bxlen, att1, att2, faW, fab, alpha, out_alphas);
    k_awe<<<BB * 9, 256, 0, stream>>>(t, bxlen, bx, embW, imgs_bf, alpha, gate, x_bf);
    k_gates<<<dim3(G4 / 16, 4), 64, 0, stream>>>(Wih_bf, x_bf, gates_p);
    k_lstm<<<(BB * DEC) / 256, 256, 0, stream>>>(t, bxlen, gates_p, bih, hWhh, h_bf, c);
    k_fc<<<VV / 16, 64, 0, stream>>>(t, bxlen, fcW_bf, fcb, h_bf, out_preds);
  }
}

// Round 6
// 6785.715 us; speedup vs baseline: 4.4055x; 1.0682x over previous
//
#include <hip/hip_runtime.h>
#include <hip/hip_bf16.h>

#define BB 32
#define TT 128
#define PP 196
#define ENC 2048
#define DEC 512
#define ATT 512
#define EMB 512
#define VV 10000
#define G4 2048   // 4*DEC
#define KX 2560   // EMB+ENC

typedef unsigned short u16;
typedef unsigned int u32;
typedef __attribute__((ext_vector_type(8))) short short8;
typedef __attribute__((ext_vector_type(4))) float f32x4;

__device__ __forceinline__ float bf2f(u16 u) { return __uint_as_float(((u32)u) << 16); }
__device__ __forceinline__ u16 f2bf(float f) {
  u32 x = __float_as_uint(f);
  u32 r = (x + 0x7fffu + ((x >> 16) & 1u)) >> 16;
  return (u16)r;
}
__device__ __forceinline__ void unpack8(uint4 v, float* f) {
  f[0] = __uint_as_float(v.x << 16); f[1] = __uint_as_float(v.x & 0xffff0000u);
  f[2] = __uint_as_float(v.y << 16); f[3] = __uint_as_float(v.y & 0xffff0000u);
  f[4] = __uint_as_float(v.z << 16); f[5] = __uint_as_float(v.z & 0xffff0000u);
  f[6] = __uint_as_float(v.w << 16); f[7] = __uint_as_float(v.w & 0xffff0000u);
}
__device__ __forceinline__ void load8(const float* __restrict__ p, float* f) {
  float4 a = ((const float4*)p)[0];
  float4 b = ((const float4*)p)[1];
  f[0] = a.x; f[1] = a.y; f[2] = a.z; f[3] = a.w;
  f[4] = b.x; f[5] = b.y; f[6] = b.z; f[7] = b.w;
}
__device__ __forceinline__ float sigf(float x) { return 1.0f / (1.0f + __expf(-x)); }
__device__ __forceinline__ short8 ld_frag(const u16* __restrict__ p) {
  union { uint4 u; short8 s; } cv;
  cv.u = *(const uint4*)p;
  return cv.s;
}

// ---------- one-time f32 -> bf16 conversion ----------
__global__ __launch_bounds__(256) void k_cvt(const float* __restrict__ src, u16* __restrict__ dst, int n) {
  int i0 = (blockIdx.x * 256 + threadIdx.x) * 8;
  if (i0 >= n) return;
  float f[8]; load8(src + i0, f);
  u16 o[8];
#pragma unroll
  for (int u = 0; u < 8; u++) o[u] = f2bf(f[u]);
  *(uint4*)(dst + i0) = *(const uint4*)o;
}

// ---------- mean over p: imgs_bf -> mean_bf (32 x 2048 bf16) ----------
__global__ __launch_bounds__(256) void k_mean(const u16* __restrict__ imgs_bf, u16* __restrict__ mean_bf) {
  int b = blockIdx.x >> 2, chunk = blockIdx.x & 3;
  int ch0 = chunk * 512 + threadIdx.x * 2;
  const u32* base = (const u32*)(imgs_bf + (size_t)b * PP * ENC + ch0);
  float a0 = 0.f, a1 = 0.f;
#pragma unroll 4
  for (int p = 0; p < PP; p++) {
    u32 u = base[(size_t)p * (ENC / 2)];
    a0 += __uint_as_float(u << 16);
    a1 += __uint_as_float(u & 0xffff0000u);
  }
  const float inv = 1.0f / PP;
  u16 o[2] = { f2bf(a0 * inv), f2bf(a1 * inv) };
  *(u32*)(mean_bf + b * ENC + ch0) = *(const u32*)o;
}

// ---------- init via MFMA: [h0;c0] = mean @ [ihW;icW]^T + b  (64 j-tiles) ----------
__global__ __launch_bounds__(64) void k_init2(const u16* __restrict__ W2_bf,
    const float* __restrict__ ihb, const float* __restrict__ icb,
    const u16* __restrict__ mean_bf, u16* __restrict__ h_bf, float* __restrict__ c) {
  int lane = threadIdx.x;
  int j0 = blockIdx.x * 16;
  int m = lane & 15, quad = lane >> 4;
  const u16* arow = W2_bf + (size_t)(j0 + m) * ENC + quad * 8;
  const u16* xb0 = mean_bf + (size_t)m * ENC + quad * 8;
  const u16* xb1 = mean_bf + (size_t)(16 + m) * ENC + quad * 8;
  f32x4 acc0 = {0.f,0.f,0.f,0.f}, acc1 = {0.f,0.f,0.f,0.f};
  for (int k = 0; k < ENC; k += 32) {
    short8 a = ld_frag(arow + k);
    short8 x0 = ld_frag(xb0 + k);
    short8 x1 = ld_frag(xb1 + k);
    acc0 = __builtin_amdgcn_mfma_f32_16x16x32_bf16(a, x0, acc0, 0, 0, 0);
    acc1 = __builtin_amdgcn_mfma_f32_16x16x32_bf16(a, x1, acc1, 0, 0, 0);
  }
  int jj = j0 + quad * 4;
  int b0 = m, b1 = 16 + m;
#pragma unroll
  for (int r = 0; r < 4; r++) {
    int j = jj + r;
    if (j < 512) {
      float bia = ihb[j];
      h_bf[b0 * DEC + j] = f2bf(acc0[r] + bia);
      h_bf[b1 * DEC + j] = f2bf(acc1[r] + bia);
    } else {
      int g = j - 512;
      float bia = icb[g];
      c[b0 * DEC + g] = acc0[r] + bia;
      c[b1 * DEC + g] = acc1[r] + bia;
    }
  }
}

// ---------- att1 via MFMA: imgs_bf(6272x2048) @ encW^T -> att1 bf16 ----------
// grid 196 m-blocks (32 m each), 4 waves; wave handles 8 j-tiles x 2 m-tiles
__global__ __launch_bounds__(256) void k_att1(const u16* __restrict__ imgs_bf,
    const u16* __restrict__ encW_bf, const float* __restrict__ encb, u16* __restrict__ att1) {
  int tid = threadIdx.x;
  int wave = tid >> 6, lane = tid & 63;
  int m0 = blockIdx.x * 32;
  int lm = lane & 15, quad = lane >> 4;
  const u16* b0p = imgs_bf + (size_t)(m0 + lm) * ENC + quad * 8;
  const u16* b1p = imgs_bf + (size_t)(m0 + 16 + lm) * ENC + quad * 8;
  const u16* arow = encW_bf + (size_t)(wave * 128 + lm) * ENC + quad * 8;
  f32x4 acc[8][2];
#pragma unroll
  for (int i = 0; i < 8; i++) { acc[i][0] = (f32x4){0.f,0.f,0.f,0.f}; acc[i][1] = (f32x4){0.f,0.f,0.f,0.f}; }
  for (int k = 0; k < ENC; k += 32) {
    short8 B0 = ld_frag(b0p + k);
    short8 B1 = ld_frag(b1p + k);
#pragma unroll
    for (int i = 0; i < 8; i++) {
      short8 A = ld_frag(arow + (size_t)i * 16 * ENC + k);
      acc[i][0] = __builtin_amdgcn_mfma_f32_16x16x32_bf16(A, B0, acc[i][0], 0, 0, 0);
      acc[i][1] = __builtin_amdgcn_mfma_f32_16x16x32_bf16(A, B1, acc[i][1], 0, 0, 0);
    }
  }
#pragma unroll
  for (int i = 0; i < 8; i++) {
    int jb = wave * 128 + i * 16 + quad * 4;
#pragma unroll
    for (int r = 0; r < 4; r++) {
      int j = jb + r;
      float bia = encb[j];
      att1[(size_t)(m0 + lm) * ATT + j]      = f2bf(acc[i][0][r] + bia);
      att1[(size_t)(m0 + 16 + lm) * ATT + j] = f2bf(acc[i][1][r] + bia);
    }
  }
}

// ---------- fused stage 1: step1(t) U fc(t-1) U emb(t)  (929 blocks x 64 thr) ----------
__global__ __launch_bounds__(64) void k_stage1(int t,
    const int* __restrict__ bx, const int* __restrict__ bxlen,
    const u16* __restrict__ W3, const float* __restrict__ decb,
    const float* __restrict__ fbb, const float* __restrict__ bhh,
    const u16* __restrict__ h_bf,
    float* __restrict__ att2, float* __restrict__ gate, float* __restrict__ hWhh,
    const u16* __restrict__ fcW_bf, const float* __restrict__ fcb, float* __restrict__ preds,
    const float* __restrict__ embW, u16* __restrict__ x_bf) {
  int bid = blockIdx.x;
  int lane = threadIdx.x;
  if (bid < 288) {
    // ---- step1: att2 / gate / hWhh from h ----
    if (t >= TT) return;
    int j0 = bid * 16;
    int m = lane & 15, quad = lane >> 4;
    const u16* arow = W3 + (size_t)(j0 + m) * DEC + quad * 8;
    const u16* xb0 = h_bf + (size_t)m * DEC + quad * 8;
    const u16* xb1 = h_bf + (size_t)(16 + m) * DEC + quad * 8;
    f32x4 acc0 = {0.f,0.f,0.f,0.f}, acc1 = {0.f,0.f,0.f,0.f};
    for (int k = 0; k < DEC; k += 32) {
      short8 a = ld_frag(arow + k);
      short8 x0 = ld_frag(xb0 + k);
      short8 x1 = ld_frag(xb1 + k);
      acc0 = __builtin_amdgcn_mfma_f32_16x16x32_bf16(a, x0, acc0, 0, 0, 0);
      acc1 = __builtin_amdgcn_mfma_f32_16x16x32_bf16(a, x1, acc1, 0, 0, 0);
    }
    int jj = j0 + quad * 4;
    int b0 = m, b1 = 16 + m;
#pragma unroll
    for (int r = 0; r < 4; r++) {
      int j = jj + r;
      float v0 = acc0[r], v1 = acc1[r];
      if (j0 < ATT) {
        float bia = decb[j];
        att2[b0 * ATT + j] = v0 + bia;
        att2[b1 * ATT + j] = v1 + bia;
      } else if (j0 < ATT + ENC) {
        int g = j - ATT;
        float bia = fbb[g];
        gate[b0 * ENC + g] = sigf(v0 + bia);
        gate[b1 * ENC + g] = sigf(v1 + bia);
      } else {
        int g = j - ATT - ENC;
        float bia = bhh[g];
        hWhh[b0 * G4 + g] = v0 + bia;
        hWhh[b1 * G4 + g] = v1 + bia;
      }
    }
  } else if (bid < 913) {
    // ---- fc for previous step (t-1) ----
    if (t == 0) return;
    int tfc = t - 1;
    int j0 = (bid - 288) * 16;
    int m = lane & 15, quad = lane >> 4;
    const u16* arow = fcW_bf + (size_t)(j0 + m) * DEC + quad * 8;
    const u16* xb0 = h_bf + (size_t)m * DEC + quad * 8;
    const u16* xb1 = h_bf + (size_t)(16 + m) * DEC + quad * 8;
    f32x4 acc0 = {0.f,0.f,0.f,0.f}, acc1 = {0.f,0.f,0.f,0.f};
    for (int k = 0; k < DEC; k += 32) {
      short8 a = ld_frag(arow + k);
      short8 x0 = ld_frag(xb0 + k);
      short8 x1 = ld_frag(xb1 + k);
      acc0 = __builtin_amdgcn_mfma_f32_16x16x32_bf16(a, x0, acc0, 0, 0, 0);
      acc1 = __builtin_amdgcn_mfma_f32_16x16x32_bf16(a, x1, acc1, 0, 0, 0);
    }
    int jj = j0 + quad * 4;
    int b0 = m, b1 = 16 + m;
    bool act0 = (tfc < bxlen[b0]);
    bool act1 = (tfc < bxlen[b1]);
#pragma unroll
    for (int r = 0; r < 4; r++) {
      int j = jj + r;
      float bia = fcb[j];
      preds[((size_t)b0 * TT + tfc) * VV + j] = act0 ? (acc0[r] + bia) : 0.f;
      preds[((size_t)b1 * TT + tfc) * VV + j] = act1 ? (acc1[r] + bia) : 0.f;
    }
  } else {
    // ---- emb gather for step t into x_bf[:, 0:512] ----
    if (t >= TT) return;
    int flat = (bid - 913) * 64 + lane;   // 0..1023
    int b = flat >> 5;
    int ch0 = (flat & 31) * 16;
    int tok = bx[b * TT + t];
    const float* e = embW + (size_t)tok * EMB + ch0;
    u16 o[16];
#pragma unroll
    for (int u = 0; u < 16; u++) o[u] = f2bf(e[u]);
    *(uint4*)(x_bf + (size_t)b * KX + ch0)     = *(const uint4*)o;
    *(uint4*)(x_bf + (size_t)b * KX + ch0 + 8) = *(const uint4*)(o + 8);
  }
}

// ---------- per-step: e, softmax, alpha (one block per b) ----------
__global__ __launch_bounds__(256) void k_att(int t, const int* __restrict__ bxlen,
    const u16* __restrict__ att1, const float* __restrict__ att2,
    const float* __restrict__ faW, const float* __restrict__ fab,
    float* __restrict__ alpha_ws, float* __restrict__ out_alphas) {
  int b = blockIdx.x;
  int tid = threadIdx.x;
  if (t >= bxlen[b]) {
    if (tid < PP) out_alphas[((size_t)b * TT + t) * PP + tid] = 0.f;
    return;
  }
  __shared__ float a2[ATT];
  __shared__ float w_s[ATT];
  __shared__ float redw[4], redw2[4];
  for (int i = tid; i < ATT; i += 256) { a2[i] = att2[b * ATT + i]; w_s[i] = faW[i]; }
  __syncthreads();
  float e = -1e30f;
  if (tid < PP) {
    const uint4* ar = (const uint4*)(att1 + (size_t)(b * PP + tid) * ATT);
    float acc = 0.f;
    for (int k = 0; k < ATT; k += 8) {
      float af[8]; unpack8(ar[k >> 3], af);
#pragma unroll
      for (int u = 0; u < 8; u++) {
        float v = af[u] + a2[k + u];
        acc += fmaxf(v, 0.f) * w_s[k + u];
      }
    }
    e = acc + fab[0];
  }
  int lane = tid & 63, wid = tid >> 6;
  float wmax = e;
#pragma unroll
  for (int off = 32; off; off >>= 1) wmax = fmaxf(wmax, __shfl_xor(wmax, off));
  if (lane == 0) redw[wid] = wmax;
  __syncthreads();
  float mx = fmaxf(fmaxf(redw[0], redw[1]), fmaxf(redw[2], redw[3]));
  float ex = (tid < PP) ? __expf(e - mx) : 0.f;
  float wsum = ex;
#pragma unroll
  for (int off = 32; off; off >>= 1) wsum += __shfl_xor(wsum, off);
  if (lane == 0) redw2[wid] = wsum;
  __syncthreads();
  float inv = 1.0f / (redw2[0] + redw2[1] + redw2[2] + redw2[3]);
  if (tid < PP) {
    float al = ex * inv;
    alpha_ws[b * PP + tid] = al;
    out_alphas[((size_t)b * TT + t) * PP + tid] = al;
  }
}

// ---------- per-step: awe = alpha . imgs; x_bf[512:] = gate*awe (bf16) ----------
__global__ __launch_bounds__(256) void k_awe(int t, const int* __restrict__ bxlen,
    const u16* __restrict__ imgs_bf, const float* __restrict__ alpha_ws,
    const float* __restrict__ gate, u16* __restrict__ x_bf) {
  int b = blockIdx.x >> 2, chunk = blockIdx.x & 3;
  if (t >= bxlen[b]) return;
  __shared__ float al[PP];
  int tid = threadIdx.x;
  if (tid < PP) al[tid] = alpha_ws[b * PP + tid];
  __syncthreads();
  int ch0 = chunk * 512 + tid * 2;
  const u32* base = (const u32*)(imgs_bf + (size_t)b * PP * ENC + ch0);
  float acc0 = 0.f, acc1 = 0.f;
#pragma unroll 4
  for (int p = 0; p < PP; p++) {
    u32 u = base[(size_t)p * (ENC / 2)];
    float a = al[p];
    acc0 += a * __uint_as_float(u << 16);
    acc1 += a * __uint_as_float(u & 0xffff0000u);
  }
  float2 g = *(const float2*)(gate + b * ENC + ch0);
  u16 o[2] = { f2bf(g.x * acc0), f2bf(g.y * acc1) };
  *(u32*)(x_bf + (size_t)b * KX + EMB + ch0) = *(const u32*)o;
}

// ---------- per-step: gates partials via MFMA, split-K 4x640 ----------
__global__ __launch_bounds__(64) void k_gates(const u16* __restrict__ Wih_bf,
    const u16* __restrict__ x_bf, float* __restrict__ gates_p) {
  int lane = threadIdx.x;
  int j0 = blockIdx.x * 16;
  int kc = blockIdx.y * 640;
  int m = lane & 15, quad = lane >> 4;
  const u16* arow = Wih_bf + (size_t)(j0 + m) * KX + kc + quad * 8;
  const u16* xb0 = x_bf + (size_t)m * KX + kc + quad * 8;
  const u16* xb1 = x_bf + (size_t)(16 + m) * KX + kc + quad * 8;
  f32x4 acc0 = {0.f,0.f,0.f,0.f}, acc1 = {0.f,0.f,0.f,0.f};
  for (int k = 0; k < 640; k += 32) {
    short8 a = ld_frag(arow + k);
    short8 x0 = ld_frag(xb0 + k);
    short8 x1 = ld_frag(xb1 + k);
    acc0 = __builtin_amdgcn_mfma_f32_16x16x32_bf16(a, x0, acc0, 0, 0, 0);
    acc1 = __builtin_amdgcn_mfma_f32_16x16x32_bf16(a, x1, acc1, 0, 0, 0);
  }
  float* gp = gates_p + (size_t)blockIdx.y * BB * G4;
  int jj = j0 + quad * 4;
  int b0 = m, b1 = 16 + m;
#pragma unroll
  for (int r = 0; r < 4; r++) {
    int j = jj + r;
    gp[b0 * G4 + j] = acc0[r];
    gp[b1 * G4 + j] = acc1[r];
  }
}

// ---------- per-step: LSTM pointwise (sums split-K partials) ----------
__global__ __launch_bounds__(256) void k_lstm(int t, const int* __restrict__ bxlen,
    const float* __restrict__ gates_p, const float* __restrict__ bih,
    const float* __restrict__ hWhh,
    u16* __restrict__ h_bf, float* __restrict__ c) {
  int idx = blockIdx.x * 256 + threadIdx.x;
  int b = idx >> 9, d = idx & 511;
  if (t >= bxlen[b]) return;
  float pre[4];
#pragma unroll
  for (int g = 0; g < 4; g++) {
    int j = g * 512 + d;
    float s = bih[j] + hWhh[b * G4 + j];
#pragma unroll
    for (int cc = 0; cc < 4; cc++) s += gates_p[(size_t)cc * BB * G4 + b * G4 + j];
    pre[g] = s;
  }
  float i_ = sigf(pre[0]);
  float f_ = sigf(pre[1]);
  float g_ = tanhf(pre[2]);
  float o_ = sigf(pre[3]);
  float cn = f_ * c[b * DEC + d] + i_ * g_;
  float hn = o_ * tanhf(cn);
  c[b * DEC + d] = cn;
  h_bf[b * DEC + d] = f2bf(hn);
}

extern "C" void kernel_launch(void* const* d_in, const int* in_sizes, int n_in,
                              void* d_out, int out_size, void* d_ws, size_t ws_size,
                              hipStream_t stream) {
  const float* imgs = (const float*)d_in[0];
  const int* bx     = (const int*)d_in[1];
  const int* bxlen  = (const int*)d_in[2];
  const float* embW = (const float*)d_in[3];
  const float* encW = (const float*)d_in[4];
  const float* encb = (const float*)d_in[5];
  const float* decW = (const float*)d_in[6];
  const float* decb = (const float*)d_in[7];
  const float* faW  = (const float*)d_in[8];
  const float* fab  = (const float*)d_in[9];
  const float* ihW  = (const float*)d_in[10];
  const float* ihb  = (const float*)d_in[11];
  const float* icW  = (const float*)d_in[12];
  const float* icb  = (const float*)d_in[13];
  const float* fbW  = (const float*)d_in[14];
  const float* fbb  = (const float*)d_in[15];
  const float* Wih  = (const float*)d_in[16];
  const float* bih  = (const float*)d_in[17];
  const float* Whh  = (const float*)d_in[18];
  const float* bhh  = (const float*)d_in[19];
  const float* fcW  = (const float*)d_in[20];
  const float* fcb  = (const float*)d_in[21];

  float* out_preds  = (float*)d_out;
  float* out_alphas = out_preds + (size_t)BB * TT * VV;

  char* wsb = (char*)d_ws;
  size_t off = 0;
  u16* imgs_bf = (u16*)(wsb + off); off += (size_t)BB * PP * ENC * 2;   // 25.69 MB
  u16* W3_bf   = (u16*)(wsb + off); off += (size_t)4608 * DEC * 2;      // 4.72 MB
  u16* Wih_bf  = (u16*)(wsb + off); off += (size_t)G4 * KX * 2;         // 10.49 MB
  u16* fcW_bf  = (u16*)(wsb + off); off += (size_t)VV * DEC * 2;        // 10.24 MB
  u16* encW_bf = (u16*)(wsb + off); off += (size_t)ATT * ENC * 2;       // 2.00 MB
  u16* att1    = (u16*)(wsb + off);
  // W2_bf (4 MB) + mean_bf (128 KB) alias att1's 6.42 MB region (used only before k_att1 writes att1)
  u16* W2_bf   = att1;
  u16* mean_bf = att1 + (size_t)1024 * ENC;
  off += (size_t)BB * PP * ATT * 2;                                     // 6.42 MB
  u16* x_bf    = (u16*)(wsb + off); off += (size_t)BB * KX * 2;         // 160 KB
  u16* h_bf    = (u16*)(wsb + off); off += (size_t)BB * DEC * 2;        // 32 KB
  float* c      = (float*)(wsb + off); off += (size_t)BB * DEC * 4;
  float* att2   = (float*)(wsb + off); off += (size_t)BB * ATT * 4;
  float* gate   = (float*)(wsb + off); off += (size_t)BB * ENC * 4;
  float* hWhh   = (float*)(wsb + off); off += (size_t)BB * G4 * 4;
  float* gates_p = (float*)(wsb + off); off += (size_t)4 * BB * G4 * 4; // 1 MB
  float* alpha  = (float*)(wsb + off); off += (size_t)BB * PP * 4;

  // one-time conversions
  k_cvt<<<(BB * PP * ENC) / 2048, 256, 0, stream>>>(imgs, imgs_bf, BB * PP * ENC);
  k_cvt<<<(DEC * DEC) / 2048, 256, 0, stream>>>(decW, W3_bf, DEC * DEC);
  k_cvt<<<(ENC * DEC) / 2048, 256, 0, stream>>>(fbW, W3_bf + (size_t)DEC * DEC, ENC * DEC);
  k_cvt<<<(G4 * DEC) / 2048, 256, 0, stream>>>(Whh, W3_bf + (size_t)(DEC + ENC) * DEC, G4 * DEC);
  k_cvt<<<(G4 * KX) / 2048, 256, 0, stream>>>(Wih, Wih_bf, G4 * KX);
  k_cvt<<<(VV * DEC) / 2048, 256, 0, stream>>>(fcW, fcW_bf, VV * DEC);
  k_cvt<<<(ATT * ENC) / 2048, 256, 0, stream>>>(encW, encW_bf, ATT * ENC);
  k_cvt<<<(DEC * ENC) / 2048, 256, 0, stream>>>(ihW, W2_bf, DEC * ENC);
  k_cvt<<<(DEC * ENC) / 2048, 256, 0, stream>>>(icW, W2_bf + (size_t)DEC * ENC, DEC * ENC);

  // init state + att1 (aliased buffers consumed before att1 write)
  k_mean<<<BB * 4, 256, 0, stream>>>(imgs_bf, mean_bf);
  k_init2<<<64, 64, 0, stream>>>(W2_bf, ihb, icb, mean_bf, h_bf, c);
  k_att1<<<(BB * PP) / 32, 256, 0, stream>>>(imgs_bf, encW_bf, encb, att1);

  for (int t = 0; t < TT; t++) {
    k_stage1<<<929, 64, 0, stream>>>(t, bx, bxlen, W3_bf, decb, fbb, bhh, h_bf,
                                     att2, gate, hWhh, fcW_bf, fcb, out_preds, embW, x_bf);
    k_att<<<BB, 256, 0, stream>>>(t, bxlen, att1, att2, faW, fab, alpha, out_alphas);
    k_awe<<<BB * 4, 256, 0, stream>>>(t, bxlen, imgs_bf, alpha, gate, x_bf);
    k_gates<<<dim3(G4 / 16, 4), 64, 0, stream>>>(Wih_bf, x_bf, gates_p);
    k_lstm<<<(BB * DEC) / 256, 256, 0, stream>>>(t, bxlen, gates_p, bih, hWhh, h_bf, c);
  }
  // final fc for t=127 (step1/emb parts self-disable at t=TT)
  k_stage1<<<929, 64, 0, stream>>>(TT, bx, bxlen, W3_bf, decb, fbb, bhh, h_bf,
                                   att2, gate, hWhh, fcW_bf, fcb, out_preds, embW, x_bf);
}